// Round 4
// baseline (210.258 us; speedup 1.0000x reference)
//
#include <hip/hip_runtime.h>

// YOLOv1 loss: batch x 7 x 7 x 30 fp32 inputs (y_trues, y_preds) -> scalar.
// ~193 MB input. History:
//   R0 (AoS, 1 atomic/block, grid=3136):        78 us; invariant cold vs warm.
//   R1 (LDS-staged coalesced, grid=3136):       74.5 us -> not transaction-bound.
//   R3 (two-stage reduce, no atomics, grid=3136): 74 us, occupancy 13% -> not
//       atomic-bound, not occupancy-sensitive.
// Every variant shares grid=3136 and lands at ~24 ns/workgroup. Theory under
// test now: fixed per-workgroup dispatch/retire cost dominates. Experiment:
// persistent blocks, grid=512 (2/CU), each block loops over ~6 tiles.
// Staging + compute code unchanged.

#define SS 49      // S*S
#define DD 30      // C + 5*B
#define BLOCK 256
#define CPB 256            // cells per tile
#define TILE_F (CPB * DD)  // 7680 floats per array per tile (30720 B)
#define PERSIST_GRID 512   // 2 blocks/CU on 256 CUs

// Async, direct global->LDS copy, 16B per lane. Dest must be linear
// (wave-uniform base + lane*16) -- our staging loop is exactly that.
__device__ __forceinline__ void g2l16(const float* g, float* l) {
    __builtin_amdgcn_global_load_lds(
        (const __attribute__((address_space(1))) void*)g,
        (__attribute__((address_space(3))) void*)l,
        16, 0, 0);
}

__device__ __forceinline__ float iou_yolo(const float b1[4], const float b2[4]) {
    const float EPS = 1e-6f;
    float b1x1 = b1[0] - b1[2] * 0.5f, b1y1 = b1[1] - b1[3] * 0.5f;
    float b1x2 = b1[0] + b1[2] * 0.5f, b1y2 = b1[1] + b1[3] * 0.5f;
    float b2x1 = b2[0] - b2[2] * 0.5f, b2y1 = b2[1] - b2[3] * 0.5f;
    float b2x2 = b2[0] + b2[2] * 0.5f, b2y2 = b2[1] + b2[3] * 0.5f;
    float iw = fmaxf(fminf(b1x2, b2x2) - fmaxf(b1x1, b2x1), 0.0f);
    float ih = fmaxf(fminf(b1y2, b2y2) - fmaxf(b1y1, b2y1), 0.0f);
    float inter = iw * ih;
    float a1 = fabsf((b1x2 - b1x1) * (b1y2 - b1y1));
    float a2 = fabsf((b2x2 - b2x1) * (b2y2 - b2y1));
    return inter / (a1 + a2 - inter + EPS);
}

// Core per-cell loss from LDS-staged rows (unchanged since R1, verified).
__device__ __forceinline__ float cell_loss(const float* __restrict__ yt,
                                           const float* __restrict__ yp) {
    const float LAMBDA_COORD = 5.0f;
    const float LAMBDA_NOOBJ = 0.5f;
    const float EPS = 1e-6f;

    float obj = (yt[4] == 1.0f) ? 1.0f : 0.0f;
    float noobj = 1.0f - obj;

    float tb[4]  = {yt[0], yt[1], yt[2], yt[3]};
    float pb1[4] = {yp[0], yp[1], yp[2], yp[3]};
    float pb2[4] = {yp[5], yp[6], yp[7], yp[8]};
    float iou1 = iou_yolo(tb, pb1);
    float iou2 = iou_yolo(tb, pb2);
    bool best1 = iou1 > iou2;

    float bh0 = best1 ? yp[0] : yp[5];
    float bh1 = best1 ? yp[1] : yp[6];
    float bh2 = best1 ? yp[2] : yp[7];
    float bh3 = best1 ? yp[3] : yp[8];
    float conf_hat       = best1 ? yp[4] : yp[9];
    float other_conf_hat = best1 ? yp[9] : yp[4];

    float dx = yt[0] - bh0, dy = yt[1] - bh1;
    float xy = dx * dx + dy * dy;

    float sw = sqrtf(yt[2]) - sqrtf(fabsf(bh2 + EPS));
    float sh = sqrtf(yt[3]) - sqrtf(fabsf(bh3 + EPS));
    float wh = sw * sw + sh * sh;

    float dc = yt[4] - conf_hat;
    float obj_conf = dc * dc;

    float noobj_in_obj = LAMBDA_NOOBJ * other_conf_hat * other_conf_hat;

    float d4 = yt[4] - yp[4];
    float d9 = yt[4] - yp[9];
    float noobj_cells = LAMBDA_NOOBJ * (d4 * d4 + d9 * d9);

    float cls = 0.0f;
#pragma unroll
    for (int k = 10; k < DD; ++k) {
        float d = yt[k] - yp[k];
        cls += d * d;
    }

    return obj * (LAMBDA_COORD * (xy + wh) + obj_conf + noobj_in_obj + cls)
         + noobj * noobj_cells;
}

// Persistent blocks: each block grid-strides over 256-cell tiles.
// USE_WS=1: per-block partial -> partials[blockIdx.x]; USE_WS=0: atomic.
template <int USE_WS>
__global__ __launch_bounds__(BLOCK)
void yolo_loss_kernel(const float* __restrict__ yt_g,
                      const float* __restrict__ yp_g,
                      float* __restrict__ sink,
                      int ncells, int ntiles, float inv_batch) {
    __shared__ __align__(16) float lt[TILE_F];
    __shared__ __align__(16) float lp[TILE_F];
    __shared__ float smem[BLOCK / 64];

    const int tid = threadIdx.x;
    const int lane = tid & 63;
    const int wave = tid >> 6;
    float block_sum = 0.0f;

    for (int t = blockIdx.x; t < ntiles; t += gridDim.x) {
        const int base_cell = t * CPB;
        const int nc = min(CPB, ncells - base_cell);
        const int nf = nc * DD;
        const int nf4 = nf >> 2;
        const size_t base_f = (size_t)base_cell * DD;

        const float* gt = yt_g + base_f;
        const float* gp = yp_g + base_f;

        // Coalesced staging: lane i copies 16B at a linear LDS offset.
        for (int j = tid; j < nf4; j += BLOCK) {
            g2l16(gt + 4 * j, &lt[4 * j]);
            g2l16(gp + 4 * j, &lp[4 * j]);
        }
        for (int j = (nf4 << 2) + tid; j < nf; j += BLOCK) {  // tail, dormant
            lt[j] = gt[j];
            lp[j] = gp[j];
        }
        __syncthreads();  // drains vmcnt (incl. global_load_lds)

        float per_cell = 0.0f;
        if (tid < nc) per_cell = cell_loss(&lt[tid * DD], &lp[tid * DD]);

#pragma unroll
        for (int off = 32; off > 0; off >>= 1)
            per_cell += __shfl_down(per_cell, off, 64);

        if (lane == 0) smem[wave] = per_cell;
        __syncthreads();  // smem ready; also fences lt/lp reuse next iter
        if (tid == 0)
            block_sum += smem[0] + smem[1] + smem[2] + smem[3];
        // No extra barrier needed: next iteration's staging barrier orders
        // thread 0's smem read before the next smem writes.
    }

    if (tid == 0) {
        if (USE_WS) sink[blockIdx.x] = block_sum;
        else        atomicAdd(sink, block_sum * inv_batch);
    }
}

// Second stage: one block sums the per-block partials and writes the scalar.
__global__ __launch_bounds__(256)
void reduce_kernel(const float* __restrict__ partials, float* __restrict__ out,
                   int n, float inv_batch) {
    float s = 0.0f;
    for (int i = threadIdx.x; i < n; i += 256) s += partials[i];
#pragma unroll
    for (int off = 32; off > 0; off >>= 1)
        s += __shfl_down(s, off, 64);
    __shared__ float sm[4];
    int lane = threadIdx.x & 63;
    int wave = threadIdx.x >> 6;
    if (lane == 0) sm[wave] = s;
    __syncthreads();
    if (threadIdx.x == 0)
        out[0] = (sm[0] + sm[1] + sm[2] + sm[3]) * inv_batch;
}

extern "C" void kernel_launch(void* const* d_in, const int* in_sizes, int n_in,
                              void* d_out, int out_size, void* d_ws, size_t ws_size,
                              hipStream_t stream) {
    const float* yt = (const float*)d_in[0];
    const float* yp = (const float*)d_in[1];
    float* out = (float*)d_out;
    float* ws = (float*)d_ws;

    int total = in_sizes[0];          // batch * S*S * D
    int ncells = total / DD;          // batch * 49
    int batch = ncells / SS;
    float inv_batch = 1.0f / (float)batch;

    int ntiles = (ncells + CPB - 1) / CPB;
    int grid = ntiles < PERSIST_GRID ? ntiles : PERSIST_GRID;

    if (ws != nullptr && ws_size >= (size_t)grid * sizeof(float)) {
        yolo_loss_kernel<1><<<grid, BLOCK, 0, stream>>>(yt, yp, ws, ncells,
                                                        ntiles, inv_batch);
        reduce_kernel<<<1, 256, 0, stream>>>(ws, out, grid, inv_batch);
    } else {
        // Fallback: atomic path (d_out is poisoned each launch -> memset).
        hipMemsetAsync(out, 0, sizeof(float), stream);
        yolo_loss_kernel<0><<<grid, BLOCK, 0, stream>>>(yt, yp, out, ncells,
                                                        ntiles, inv_batch);
    }
}

// Round 5
// 206.669 us; speedup vs baseline: 1.0174x; 1.0174x over previous
//
#include <hip/hip_runtime.h>

// YOLOv1 loss: batch x 7 x 7 x 30 fp32 inputs (y_trues, y_preds) -> scalar.
// ~193 MB input. History (kernel time, cold):
//   R0 AoS scattered loads, grid=3136:        78 us  (TA: ~120 lines/wave-load)
//   R1 gload_lds + per-tile barrier:          74.5 us
//   R3 + two-stage reduce (no atomics):       74 us  (occupancy 13% -- no change)
//   R4 + persistent 512 blocks:               74 us  (not WG-dispatch overhead)
// Diagnosis: every staged variant serializes {issue 60KB -> syncthreads
// (vmcnt(0) drain) -> compute} with ~1 block/CU resident: full memory latency
// exposed per tile, per-CU ingest ~4 B/cy. R0 instead hit the TA transaction
// wall. This version removes both: WAVE-PRIVATE LDS tiles, no barriers in the
// main loop, coalesced float2 loads -> VGPR -> ds_write. 8 free-running
// waves/CU, ~15 KB in flight each -> latency covered by wave overlap.

#define SS 49      // S*S
#define DD 30      // C + 5*B
#define BLOCK 256
#define WPB 4              // waves per block
#define CPW 64             // cells per wave per round
#define FPW (CPW * DD)     // 1920 floats per array per wave-round
#define F2PW (FPW / 2)     // 960 float2 per array per wave-round
#define PERSIST_GRID 512   // 2 blocks/CU on 256 CUs

__device__ __forceinline__ float iou_yolo(const float b1[4], const float b2[4]) {
    const float EPS = 1e-6f;
    float b1x1 = b1[0] - b1[2] * 0.5f, b1y1 = b1[1] - b1[3] * 0.5f;
    float b1x2 = b1[0] + b1[2] * 0.5f, b1y2 = b1[1] + b1[3] * 0.5f;
    float b2x1 = b2[0] - b2[2] * 0.5f, b2y1 = b2[1] - b2[3] * 0.5f;
    float b2x2 = b2[0] + b2[2] * 0.5f, b2y2 = b2[1] + b2[3] * 0.5f;
    float iw = fmaxf(fminf(b1x2, b2x2) - fmaxf(b1x1, b2x1), 0.0f);
    float ih = fmaxf(fminf(b1y2, b2y2) - fmaxf(b1y1, b2y1), 0.0f);
    float inter = iw * ih;
    float a1 = fabsf((b1x2 - b1x1) * (b1y2 - b1y1));
    float a2 = fabsf((b2x2 - b2x1) * (b2y2 - b2y1));
    return inter / (a1 + a2 - inter + EPS);
}

// Core per-cell loss from LDS-staged rows (unchanged since R1, verified).
__device__ __forceinline__ float cell_loss(const float* __restrict__ yt,
                                           const float* __restrict__ yp) {
    const float LAMBDA_COORD = 5.0f;
    const float LAMBDA_NOOBJ = 0.5f;
    const float EPS = 1e-6f;

    float obj = (yt[4] == 1.0f) ? 1.0f : 0.0f;
    float noobj = 1.0f - obj;

    float tb[4]  = {yt[0], yt[1], yt[2], yt[3]};
    float pb1[4] = {yp[0], yp[1], yp[2], yp[3]};
    float pb2[4] = {yp[5], yp[6], yp[7], yp[8]};
    float iou1 = iou_yolo(tb, pb1);
    float iou2 = iou_yolo(tb, pb2);
    bool best1 = iou1 > iou2;

    float bh0 = best1 ? yp[0] : yp[5];
    float bh1 = best1 ? yp[1] : yp[6];
    float bh2 = best1 ? yp[2] : yp[7];
    float bh3 = best1 ? yp[3] : yp[8];
    float conf_hat       = best1 ? yp[4] : yp[9];
    float other_conf_hat = best1 ? yp[9] : yp[4];

    float dx = yt[0] - bh0, dy = yt[1] - bh1;
    float xy = dx * dx + dy * dy;

    float sw = sqrtf(yt[2]) - sqrtf(fabsf(bh2 + EPS));
    float sh = sqrtf(yt[3]) - sqrtf(fabsf(bh3 + EPS));
    float wh = sw * sw + sh * sh;

    float dc = yt[4] - conf_hat;
    float obj_conf = dc * dc;

    float noobj_in_obj = LAMBDA_NOOBJ * other_conf_hat * other_conf_hat;

    float d4 = yt[4] - yp[4];
    float d9 = yt[4] - yp[9];
    float noobj_cells = LAMBDA_NOOBJ * (d4 * d4 + d9 * d9);

    float cls = 0.0f;
#pragma unroll
    for (int k = 10; k < DD; ++k) {
        float d = yt[k] - yp[k];
        cls += d * d;
    }

    return obj * (LAMBDA_COORD * (xy + wh) + obj_conf + noobj_in_obj + cls)
         + noobj * noobj_cells;
}

// Persistent free-running waves. Each wave owns a private 2x7680B LDS region
// and grid-strides over 64-cell tiles. NO __syncthreads in the main loop:
// intra-wave ds_write -> ds_read ordering is lgkmcnt, handled by compiler.
// USE_WS=1: per-block partial -> partials[blockIdx.x]; USE_WS=0: atomic.
template <int USE_WS>
__global__ __launch_bounds__(BLOCK)
void yolo_loss_kernel(const float* __restrict__ yt_g,
                      const float* __restrict__ yp_g,
                      float* __restrict__ sink,
                      int ncells, float inv_batch) {
    // 4 waves x (1920+1920) floats = 61440 B (< 64 KB static limit).
    __shared__ __align__(16) float lt[WPB][FPW];
    __shared__ __align__(16) float lp[WPB][FPW];
    __shared__ float smem[WPB];

    const int tid  = threadIdx.x;
    const int lane = tid & 63;
    const int wave = tid >> 6;
    const int gwave  = blockIdx.x * WPB + wave;
    const int nwaves = gridDim.x * WPB;
    const int nwt = (ncells + CPW - 1) / CPW;  // 64-cell wave-tiles

    float* __restrict__ ltw = lt[wave];
    float* __restrict__ lpw = lp[wave];
    float2* __restrict__ ltw2 = reinterpret_cast<float2*>(ltw);
    float2* __restrict__ lpw2 = reinterpret_cast<float2*>(lpw);

    float wsum = 0.0f;

    for (int wt = gwave; wt < nwt; wt += nwaves) {
        const int cb = wt * CPW;  // first cell of this wave-tile
        const size_t f2b = (size_t)cb * (DD / 2);
        const float2* gt2 = reinterpret_cast<const float2*>(yt_g) + f2b;
        const float2* gp2 = reinterpret_cast<const float2*>(yp_g) + f2b;
        const int ncf2 = min(CPW, ncells - cb) * (DD / 2);

        if (ncf2 == F2PW) {
            // Full tile: 15 coalesced float2 per lane per array. All 30 loads
            // issue before the ds_writes consume them (compiler vmcnt waits),
            // keeping ~15 KB in flight per wave.
#pragma unroll
            for (int i = 0; i < F2PW / 64; ++i) {
                int idx = i * 64 + lane;
                float2 a = gt2[idx];
                float2 b = gp2[idx];
                ltw2[idx] = a;
                lpw2[idx] = b;
            }
        } else {
            // Tail tile (dormant for bench shapes: 802816 % 64 == 0).
#pragma unroll
            for (int i = 0; i < F2PW / 64; ++i) {
                int idx = i * 64 + lane;
                if (idx < ncf2) {
                    ltw2[idx] = gt2[idx];
                    lpw2[idx] = gp2[idx];
                }
            }
        }

        // Wave-private region: no barrier needed before reading.
        int c = cb + lane;
        if (c < ncells)
            wsum += cell_loss(&ltw[lane * DD], &lpw[lane * DD]);
    }

    // Final reduction: wave shuffle-reduce, one cross-wave barrier, one store.
#pragma unroll
    for (int off = 32; off > 0; off >>= 1)
        wsum += __shfl_down(wsum, off, 64);

    if (lane == 0) smem[wave] = wsum;
    __syncthreads();
    if (tid == 0) {
        float s = smem[0] + smem[1] + smem[2] + smem[3];
        if (USE_WS) sink[blockIdx.x] = s;
        else        atomicAdd(sink, s * inv_batch);
    }
}

// Second stage: one block sums the per-block partials and writes the scalar.
__global__ __launch_bounds__(256)
void reduce_kernel(const float* __restrict__ partials, float* __restrict__ out,
                   int n, float inv_batch) {
    float s = 0.0f;
    for (int i = threadIdx.x; i < n; i += 256) s += partials[i];
#pragma unroll
    for (int off = 32; off > 0; off >>= 1)
        s += __shfl_down(s, off, 64);
    __shared__ float sm[4];
    int lane = threadIdx.x & 63;
    int wave = threadIdx.x >> 6;
    if (lane == 0) sm[wave] = s;
    __syncthreads();
    if (threadIdx.x == 0)
        out[0] = (sm[0] + sm[1] + sm[2] + sm[3]) * inv_batch;
}

extern "C" void kernel_launch(void* const* d_in, const int* in_sizes, int n_in,
                              void* d_out, int out_size, void* d_ws, size_t ws_size,
                              hipStream_t stream) {
    const float* yt = (const float*)d_in[0];
    const float* yp = (const float*)d_in[1];
    float* out = (float*)d_out;
    float* ws = (float*)d_ws;

    int total = in_sizes[0];          // batch * S*S * D
    int ncells = total / DD;          // batch * 49
    int batch = ncells / SS;
    float inv_batch = 1.0f / (float)batch;

    int nwt = (ncells + CPW - 1) / CPW;
    int grid_needed = (nwt + WPB - 1) / WPB;
    int grid = grid_needed < PERSIST_GRID ? grid_needed : PERSIST_GRID;

    if (ws != nullptr && ws_size >= (size_t)grid * sizeof(float)) {
        yolo_loss_kernel<1><<<grid, BLOCK, 0, stream>>>(yt, yp, ws, ncells,
                                                        inv_batch);
        reduce_kernel<<<1, 256, 0, stream>>>(ws, out, grid, inv_batch);
    } else {
        // Fallback: atomic path (d_out is poisoned each launch -> memset).
        hipMemsetAsync(out, 0, sizeof(float), stream);
        yolo_loss_kernel<0><<<grid, BLOCK, 0, stream>>>(yt, yp, out, ncells,
                                                        inv_batch);
    }
}

// Round 6
// 204.874 us; speedup vs baseline: 1.0263x; 1.0088x over previous
//
#include <hip/hip_runtime.h>

// YOLOv1 loss: batch x 7 x 7 x 30 fp32 inputs (y_trues, y_preds) -> scalar.
// ~193 MB input. History (kernel time, cold):
//   R0 AoS scattered, grid=3136:            78 us
//   R1 gload_lds + per-tile barrier:        74.5 us
//   R3 + two-stage reduce (no atomics):     74 us
//   R4 + persistent 512 blocks:             74 us
//   R5 wave-private LDS, no barriers:       74 us
// Diagnosis (R5 counters): per-CU ingest pinned at 4.2 B/cy in ALL variants.
// R5's 29 kcy/tile ~= 30 loads x 950 cy: compiler fused each ds_write to its
// load (VGPR=88 -> vmcnt-serialized chain), so each wave keeps ONE 512B load
// in flight; 8 waves x 512B / 950cy = 4.3 B/cy = measured. Zero MLP is the
// wall, not coalescing/atomics/WG-overhead/barriers.
// Fix: phase-split staging -- 15 float2 into named registers (all loads
// issued back-to-back), sched_barrier(0), then all ds_writes. ~7.7 KB in
// flight per wave per phase, 8 waves/CU -> per-CU MLP >> Little's-law need.

#define SS 49      // S*S
#define DD 30      // C + 5*B
#define BLOCK 256
#define WPB 4              // waves per block
#define CPW 64             // cells per wave per round
#define FPW (CPW * DD)     // 1920 floats per array per wave-round
#define F2PW (FPW / 2)     // 960 float2 per array per wave-round
#define LPL 15             // float2 loads per lane per array (960/64)
#define PERSIST_GRID 512   // 2 blocks/CU on 256 CUs

__device__ __forceinline__ float iou_yolo(const float b1[4], const float b2[4]) {
    const float EPS = 1e-6f;
    float b1x1 = b1[0] - b1[2] * 0.5f, b1y1 = b1[1] - b1[3] * 0.5f;
    float b1x2 = b1[0] + b1[2] * 0.5f, b1y2 = b1[1] + b1[3] * 0.5f;
    float b2x1 = b2[0] - b2[2] * 0.5f, b2y1 = b2[1] - b2[3] * 0.5f;
    float b2x2 = b2[0] + b2[2] * 0.5f, b2y2 = b2[1] + b2[3] * 0.5f;
    float iw = fmaxf(fminf(b1x2, b2x2) - fmaxf(b1x1, b2x1), 0.0f);
    float ih = fmaxf(fminf(b1y2, b2y2) - fmaxf(b1y1, b2y1), 0.0f);
    float inter = iw * ih;
    float a1 = fabsf((b1x2 - b1x1) * (b1y2 - b1y1));
    float a2 = fabsf((b2x2 - b2x1) * (b2y2 - b2y1));
    return inter / (a1 + a2 - inter + EPS);
}

// Core per-cell loss from LDS-staged rows (unchanged since R1, verified).
__device__ __forceinline__ float cell_loss(const float* __restrict__ yt,
                                           const float* __restrict__ yp) {
    const float LAMBDA_COORD = 5.0f;
    const float LAMBDA_NOOBJ = 0.5f;
    const float EPS = 1e-6f;

    float obj = (yt[4] == 1.0f) ? 1.0f : 0.0f;
    float noobj = 1.0f - obj;

    float tb[4]  = {yt[0], yt[1], yt[2], yt[3]};
    float pb1[4] = {yp[0], yp[1], yp[2], yp[3]};
    float pb2[4] = {yp[5], yp[6], yp[7], yp[8]};
    float iou1 = iou_yolo(tb, pb1);
    float iou2 = iou_yolo(tb, pb2);
    bool best1 = iou1 > iou2;

    float bh0 = best1 ? yp[0] : yp[5];
    float bh1 = best1 ? yp[1] : yp[6];
    float bh2 = best1 ? yp[2] : yp[7];
    float bh3 = best1 ? yp[3] : yp[8];
    float conf_hat       = best1 ? yp[4] : yp[9];
    float other_conf_hat = best1 ? yp[9] : yp[4];

    float dx = yt[0] - bh0, dy = yt[1] - bh1;
    float xy = dx * dx + dy * dy;

    float sw = sqrtf(yt[2]) - sqrtf(fabsf(bh2 + EPS));
    float sh = sqrtf(yt[3]) - sqrtf(fabsf(bh3 + EPS));
    float wh = sw * sw + sh * sh;

    float dc = yt[4] - conf_hat;
    float obj_conf = dc * dc;

    float noobj_in_obj = LAMBDA_NOOBJ * other_conf_hat * other_conf_hat;

    float d4 = yt[4] - yp[4];
    float d9 = yt[4] - yp[9];
    float noobj_cells = LAMBDA_NOOBJ * (d4 * d4 + d9 * d9);

    float cls = 0.0f;
#pragma unroll
    for (int k = 10; k < DD; ++k) {
        float d = yt[k] - yp[k];
        cls += d * d;
    }

    return obj * (LAMBDA_COORD * (xy + wh) + obj_conf + noobj_in_obj + cls)
         + noobj * noobj_cells;
}

// Phase-split staging of one array's wave-tile: issue all LPL loads into
// registers, THEN write them to LDS. sched_barrier(0) pins the boundary so
// the compiler cannot re-fuse load->write pairs (the R5 serialization bug).
__device__ __forceinline__ void stage_array(const float2* __restrict__ g2,
                                            float2* __restrict__ l2,
                                            int lane) {
    float2 r[LPL];
#pragma unroll
    for (int i = 0; i < LPL; ++i)
        r[i] = g2[i * 64 + lane];          // coalesced, independent loads
    __builtin_amdgcn_sched_barrier(0);     // all loads issued before writes
#pragma unroll
    for (int i = 0; i < LPL; ++i)
        l2[i * 64 + lane] = r[i];          // ds_writes drain vmcnt in order
}

// Persistent free-running waves; wave-private LDS; no barriers in main loop.
// USE_WS=1: per-block partial -> partials[blockIdx.x]; USE_WS=0: atomic.
template <int USE_WS>
__global__ __launch_bounds__(BLOCK)
void yolo_loss_kernel(const float* __restrict__ yt_g,
                      const float* __restrict__ yp_g,
                      float* __restrict__ sink,
                      int ncells, float inv_batch) {
    // 4 waves x (1920+1920) floats = 61440 B (2 blocks/CU at 160 KB).
    __shared__ __align__(16) float lt[WPB][FPW];
    __shared__ __align__(16) float lp[WPB][FPW];
    __shared__ float smem[WPB];

    const int tid  = threadIdx.x;
    const int lane = tid & 63;
    const int wave = tid >> 6;
    const int gwave  = blockIdx.x * WPB + wave;
    const int nwaves = gridDim.x * WPB;
    const int nwt = (ncells + CPW - 1) / CPW;  // 64-cell wave-tiles

    float* __restrict__ ltw = lt[wave];
    float* __restrict__ lpw = lp[wave];
    float2* __restrict__ ltw2 = reinterpret_cast<float2*>(ltw);
    float2* __restrict__ lpw2 = reinterpret_cast<float2*>(lpw);

    float wsum = 0.0f;

    for (int wt = gwave; wt < nwt; wt += nwaves) {
        const int cb = wt * CPW;  // first cell of this wave-tile
        const size_t f2b = (size_t)cb * (DD / 2);
        const float2* gt2 = reinterpret_cast<const float2*>(yt_g) + f2b;
        const float2* gp2 = reinterpret_cast<const float2*>(yp_g) + f2b;
        const int ncf2 = min(CPW, ncells - cb) * (DD / 2);

        if (ncf2 == F2PW) {
            stage_array(gt2, ltw2, lane);
            stage_array(gp2, lpw2, lane);
        } else {
            // Tail tile (dormant for bench shapes: 802816 % 64 == 0).
#pragma unroll
            for (int i = 0; i < LPL; ++i) {
                int idx = i * 64 + lane;
                if (idx < ncf2) {
                    ltw2[idx] = gt2[idx];
                    lpw2[idx] = gp2[idx];
                }
            }
        }

        // Wave-private region: intra-wave ds ordering via lgkmcnt only.
        int c = cb + lane;
        if (c < ncells)
            wsum += cell_loss(&ltw[lane * DD], &lpw[lane * DD]);
    }

    // Final reduction: wave shuffle-reduce, one cross-wave barrier, one store.
#pragma unroll
    for (int off = 32; off > 0; off >>= 1)
        wsum += __shfl_down(wsum, off, 64);

    if (lane == 0) smem[wave] = wsum;
    __syncthreads();
    if (tid == 0) {
        float s = smem[0] + smem[1] + smem[2] + smem[3];
        if (USE_WS) sink[blockIdx.x] = s;
        else        atomicAdd(sink, s * inv_batch);
    }
}

// Second stage: one block sums the per-block partials and writes the scalar.
__global__ __launch_bounds__(256)
void reduce_kernel(const float* __restrict__ partials, float* __restrict__ out,
                   int n, float inv_batch) {
    float s = 0.0f;
    for (int i = threadIdx.x; i < n; i += 256) s += partials[i];
#pragma unroll
    for (int off = 32; off > 0; off >>= 1)
        s += __shfl_down(s, off, 64);
    __shared__ float sm[4];
    int lane = threadIdx.x & 63;
    int wave = threadIdx.x >> 6;
    if (lane == 0) sm[wave] = s;
    __syncthreads();
    if (threadIdx.x == 0)
        out[0] = (sm[0] + sm[1] + sm[2] + sm[3]) * inv_batch;
}

extern "C" void kernel_launch(void* const* d_in, const int* in_sizes, int n_in,
                              void* d_out, int out_size, void* d_ws, size_t ws_size,
                              hipStream_t stream) {
    const float* yt = (const float*)d_in[0];
    const float* yp = (const float*)d_in[1];
    float* out = (float*)d_out;
    float* ws = (float*)d_ws;

    int total = in_sizes[0];          // batch * S*S * D
    int ncells = total / DD;          // batch * 49
    int batch = ncells / SS;
    float inv_batch = 1.0f / (float)batch;

    int nwt = (ncells + CPW - 1) / CPW;
    int grid_needed = (nwt + WPB - 1) / WPB;
    int grid = grid_needed < PERSIST_GRID ? grid_needed : PERSIST_GRID;

    if (ws != nullptr && ws_size >= (size_t)grid * sizeof(float)) {
        yolo_loss_kernel<1><<<grid, BLOCK, 0, stream>>>(yt, yp, ws, ncells,
                                                        inv_batch);
        reduce_kernel<<<1, 256, 0, stream>>>(ws, out, grid, inv_batch);
    } else {
        // Fallback: atomic path (d_out is poisoned each launch -> memset).
        hipMemsetAsync(out, 0, sizeof(float), stream);
        yolo_loss_kernel<0><<<grid, BLOCK, 0, stream>>>(yt, yp, out, ncells,
                                                        inv_batch);
    }
}

// Round 7
// 187.022 us; speedup vs baseline: 1.1242x; 1.0954x over previous
//
#include <hip/hip_runtime.h>

// YOLOv1 loss: batch x 7 x 7 x 30 fp32 inputs (y_trues, y_preds) -> scalar.
// ~193 MB input. History (kernel time, cold):
//   R0 AoS scattered, grid=3136:            78 us   (2.47 TB/s total ingest)
//   R1 gload_lds + per-tile barrier:        74.5 us
//   R3 + two-stage reduce (no atomics):     74 us
//   R4 + persistent 512 blocks:             74 us
//   R5 wave-private LDS, no barriers:       74 us
//   R6 + phase-split staging (reg MLP):     73 us   (2.64 TB/s total ingest)
// Model that fits ALL rounds: total ingest (HBM + L3 hits) is capped at
// ~2.6 TB/s; 193 MB / 2.6 TB/s = 74 us. Invariant to coalescing, atomics,
// WG count, barriers, MLP -> the cap is upstream of the CUs (shared fabric
// ceiling for the L3-hit+HBM mix, or DVFS: each dispatch sits between ~131us
// of near-idle harness resets, so fclk may never ramp).
// This round: LAST untested lever -- nontemporal loads. If the wall is the
// L3-allocation path specifically, nt routes the stream to HBM (FETCH_SIZE
// ~190 MB, ~4+ TB/s, ~40 us). If unchanged/worse -> environmental roofline.

#define SS 49      // S*S
#define DD 30      // C + 5*B
#define BLOCK 256
#define WPB 4              // waves per block
#define CPW 64             // cells per wave per round
#define FPW (CPW * DD)     // 1920 floats per array per wave-round
#define F2PW (FPW / 2)     // 960 float2 per array per wave-round
#define LPL 15             // 8B loads per lane per array (960/64)
#define PERSIST_GRID 512   // 2 blocks/CU on 256 CUs

typedef unsigned long long u64;

__device__ __forceinline__ float iou_yolo(const float b1[4], const float b2[4]) {
    const float EPS = 1e-6f;
    float b1x1 = b1[0] - b1[2] * 0.5f, b1y1 = b1[1] - b1[3] * 0.5f;
    float b1x2 = b1[0] + b1[2] * 0.5f, b1y2 = b1[1] + b1[3] * 0.5f;
    float b2x1 = b2[0] - b2[2] * 0.5f, b2y1 = b2[1] - b2[3] * 0.5f;
    float b2x2 = b2[0] + b2[2] * 0.5f, b2y2 = b2[1] + b2[3] * 0.5f;
    float iw = fmaxf(fminf(b1x2, b2x2) - fmaxf(b1x1, b2x1), 0.0f);
    float ih = fmaxf(fminf(b1y2, b2y2) - fmaxf(b1y1, b2y1), 0.0f);
    float inter = iw * ih;
    float a1 = fabsf((b1x2 - b1x1) * (b1y2 - b1y1));
    float a2 = fabsf((b2x2 - b2x1) * (b2y2 - b2y1));
    return inter / (a1 + a2 - inter + EPS);
}

// Core per-cell loss from LDS-staged rows (unchanged since R1, verified).
__device__ __forceinline__ float cell_loss(const float* __restrict__ yt,
                                           const float* __restrict__ yp) {
    const float LAMBDA_COORD = 5.0f;
    const float LAMBDA_NOOBJ = 0.5f;
    const float EPS = 1e-6f;

    float obj = (yt[4] == 1.0f) ? 1.0f : 0.0f;
    float noobj = 1.0f - obj;

    float tb[4]  = {yt[0], yt[1], yt[2], yt[3]};
    float pb1[4] = {yp[0], yp[1], yp[2], yp[3]};
    float pb2[4] = {yp[5], yp[6], yp[7], yp[8]};
    float iou1 = iou_yolo(tb, pb1);
    float iou2 = iou_yolo(tb, pb2);
    bool best1 = iou1 > iou2;

    float bh0 = best1 ? yp[0] : yp[5];
    float bh1 = best1 ? yp[1] : yp[6];
    float bh2 = best1 ? yp[2] : yp[7];
    float bh3 = best1 ? yp[3] : yp[8];
    float conf_hat       = best1 ? yp[4] : yp[9];
    float other_conf_hat = best1 ? yp[9] : yp[4];

    float dx = yt[0] - bh0, dy = yt[1] - bh1;
    float xy = dx * dx + dy * dy;

    float sw = sqrtf(yt[2]) - sqrtf(fabsf(bh2 + EPS));
    float sh = sqrtf(yt[3]) - sqrtf(fabsf(bh3 + EPS));
    float wh = sw * sw + sh * sh;

    float dc = yt[4] - conf_hat;
    float obj_conf = dc * dc;

    float noobj_in_obj = LAMBDA_NOOBJ * other_conf_hat * other_conf_hat;

    float d4 = yt[4] - yp[4];
    float d9 = yt[4] - yp[9];
    float noobj_cells = LAMBDA_NOOBJ * (d4 * d4 + d9 * d9);

    float cls = 0.0f;
#pragma unroll
    for (int k = 10; k < DD; ++k) {
        float d = yt[k] - yp[k];
        cls += d * d;
    }

    return obj * (LAMBDA_COORD * (xy + wh) + obj_conf + noobj_in_obj + cls)
         + noobj * noobj_cells;
}

// Phase-split staging with NONTEMPORAL loads: issue all LPL nt-loads into
// registers, sched_barrier, then all LDS writes. nt = don't retain in
// caches; discriminates L3-path wall vs shared-fabric/DVFS cap.
__device__ __forceinline__ void stage_array_nt(const u64* __restrict__ g8,
                                               u64* __restrict__ l8,
                                               int lane) {
    u64 r[LPL];
#pragma unroll
    for (int i = 0; i < LPL; ++i)
        r[i] = __builtin_nontemporal_load(g8 + i * 64 + lane);
    __builtin_amdgcn_sched_barrier(0);     // all loads issued before writes
#pragma unroll
    for (int i = 0; i < LPL; ++i)
        l8[i * 64 + lane] = r[i];
}

// Persistent free-running waves; wave-private LDS; no barriers in main loop.
// USE_WS=1: per-block partial -> partials[blockIdx.x]; USE_WS=0: atomic.
template <int USE_WS>
__global__ __launch_bounds__(BLOCK)
void yolo_loss_kernel(const float* __restrict__ yt_g,
                      const float* __restrict__ yp_g,
                      float* __restrict__ sink,
                      int ncells, float inv_batch) {
    // 4 waves x (1920+1920) floats = 61440 B (2 blocks/CU at 160 KB).
    __shared__ __align__(16) float lt[WPB][FPW];
    __shared__ __align__(16) float lp[WPB][FPW];
    __shared__ float smem[WPB];

    const int tid  = threadIdx.x;
    const int lane = tid & 63;
    const int wave = tid >> 6;
    const int gwave  = blockIdx.x * WPB + wave;
    const int nwaves = gridDim.x * WPB;
    const int nwt = (ncells + CPW - 1) / CPW;  // 64-cell wave-tiles

    float* __restrict__ ltw = lt[wave];
    float* __restrict__ lpw = lp[wave];
    u64* __restrict__ ltw8 = reinterpret_cast<u64*>(ltw);
    u64* __restrict__ lpw8 = reinterpret_cast<u64*>(lpw);

    float wsum = 0.0f;

    for (int wt = gwave; wt < nwt; wt += nwaves) {
        const int cb = wt * CPW;  // first cell of this wave-tile
        const size_t f8b = (size_t)cb * (DD / 2);
        const u64* gt8 = reinterpret_cast<const u64*>(yt_g) + f8b;
        const u64* gp8 = reinterpret_cast<const u64*>(yp_g) + f8b;
        const int ncf8 = min(CPW, ncells - cb) * (DD / 2);

        if (ncf8 == F2PW) {
            stage_array_nt(gt8, ltw8, lane);
            stage_array_nt(gp8, lpw8, lane);
        } else {
            // Tail tile (dormant for bench shapes: 802816 % 64 == 0).
#pragma unroll
            for (int i = 0; i < LPL; ++i) {
                int idx = i * 64 + lane;
                if (idx < ncf8) {
                    ltw8[idx] = gt8[idx];
                    lpw8[idx] = gp8[idx];
                }
            }
        }

        // Wave-private region: intra-wave ds ordering via lgkmcnt only.
        int c = cb + lane;
        if (c < ncells)
            wsum += cell_loss(&ltw[lane * DD], &lpw[lane * DD]);
    }

    // Final reduction: wave shuffle-reduce, one cross-wave barrier, one store.
#pragma unroll
    for (int off = 32; off > 0; off >>= 1)
        wsum += __shfl_down(wsum, off, 64);

    if (lane == 0) smem[wave] = wsum;
    __syncthreads();
    if (tid == 0) {
        float s = smem[0] + smem[1] + smem[2] + smem[3];
        if (USE_WS) sink[blockIdx.x] = s;
        else        atomicAdd(sink, s * inv_batch);
    }
}

// Second stage: one block sums the per-block partials and writes the scalar.
__global__ __launch_bounds__(256)
void reduce_kernel(const float* __restrict__ partials, float* __restrict__ out,
                   int n, float inv_batch) {
    float s = 0.0f;
    for (int i = threadIdx.x; i < n; i += 256) s += partials[i];
#pragma unroll
    for (int off = 32; off > 0; off >>= 1)
        s += __shfl_down(s, off, 64);
    __shared__ float sm[4];
    int lane = threadIdx.x & 63;
    int wave = threadIdx.x >> 6;
    if (lane == 0) sm[wave] = s;
    __syncthreads();
    if (threadIdx.x == 0)
        out[0] = (sm[0] + sm[1] + sm[2] + sm[3]) * inv_batch;
}

extern "C" void kernel_launch(void* const* d_in, const int* in_sizes, int n_in,
                              void* d_out, int out_size, void* d_ws, size_t ws_size,
                              hipStream_t stream) {
    const float* yt = (const float*)d_in[0];
    const float* yp = (const float*)d_in[1];
    float* out = (float*)d_out;
    float* ws = (float*)d_ws;

    int total = in_sizes[0];          // batch * S*S * D
    int ncells = total / DD;          // batch * 49
    int batch = ncells / SS;
    float inv_batch = 1.0f / (float)batch;

    int nwt = (ncells + CPW - 1) / CPW;
    int grid_needed = (nwt + WPB - 1) / WPB;
    int grid = grid_needed < PERSIST_GRID ? grid_needed : PERSIST_GRID;

    if (ws != nullptr && ws_size >= (size_t)grid * sizeof(float)) {
        yolo_loss_kernel<1><<<grid, BLOCK, 0, stream>>>(yt, yp, ws, ncells,
                                                        inv_batch);
        reduce_kernel<<<1, 256, 0, stream>>>(ws, out, grid, inv_batch);
    } else {
        // Fallback: atomic path (d_out is poisoned each launch -> memset).
        hipMemsetAsync(out, 0, sizeof(float), stream);
        yolo_loss_kernel<0><<<grid, BLOCK, 0, stream>>>(yt, yp, out, ncells,
                                                        inv_batch);
    }
}

// Round 9
// 186.566 us; speedup vs baseline: 1.1270x; 1.0024x over previous
//
#include <hip/hip_runtime.h>

// YOLOv1 loss: batch x 7 x 7 x 30 fp32 (y_trues, y_preds) -> scalar. ~193 MB.
// History (kernel time, cold):
//   R0-R6: six structurally different kernels all pinned at 73-78 us
//          (~2.6 TB/s total ingest, invariant to everything).
//   R7: NONTEMPORAL loads broke the wall: kernel dropped below the harness's
//       57 us fill kernels (est ~55 us, ~3.5 TB/s). Same capture shows
//       fillBufferAligned at 6.7 TB/s (84% peak) -> chip fully clocked;
//       the old wall was the L3-retention read path, not DVFS/fabric.
//   R8: float4 nt-load pipeline -- compile error only (HIP float4 is a class,
//       not a clang vector; __builtin_nontemporal_load rejects it). This
//       round = R8 with native ext_vector_type(4). Theory unchanged:
//   (a) merged yt+yp tile, 15x 16B nt-loads/lane, 15 KB in flight/wave;
//   (b) software pipeline: ds_write(t) -> issue nt-loads(t+stride) ->
//       compute(t); loads stay in flight during compute.

#define SS 49      // S*S
#define DD 30      // C + 5*B
#define BLOCK 256
#define WPB 4              // waves per block
#define CPW 64             // cells per wave-tile
#define FPW (CPW * DD)     // 1920 floats per array per tile
#define F4PT (2 * FPW / 4) // 960 16B-chunks per tile (yt 480 | yp 480)
#define F4PL (F4PT / 64)   // 15 16B loads per lane per tile
#define HALF_F4 (FPW / 4)  // 480: boundary between yt and yp in 16B units
#define PERSIST_GRID 512   // 2 blocks/CU on 256 CUs (LDS-limited)

// Native clang vector: legal operand for __builtin_nontemporal_load.
typedef float f32x4 __attribute__((ext_vector_type(4)));

__device__ __forceinline__ float iou_yolo(const float b1[4], const float b2[4]) {
    const float EPS = 1e-6f;
    float b1x1 = b1[0] - b1[2] * 0.5f, b1y1 = b1[1] - b1[3] * 0.5f;
    float b1x2 = b1[0] + b1[2] * 0.5f, b1y2 = b1[1] + b1[3] * 0.5f;
    float b2x1 = b2[0] - b2[2] * 0.5f, b2y1 = b2[1] - b2[3] * 0.5f;
    float b2x2 = b2[0] + b2[2] * 0.5f, b2y2 = b2[1] + b2[3] * 0.5f;
    float iw = fmaxf(fminf(b1x2, b2x2) - fmaxf(b1x1, b2x1), 0.0f);
    float ih = fmaxf(fminf(b1y2, b2y2) - fmaxf(b1y1, b2y1), 0.0f);
    float inter = iw * ih;
    float a1 = fabsf((b1x2 - b1x1) * (b1y2 - b1y1));
    float a2 = fabsf((b2x2 - b2x1) * (b2y2 - b2y1));
    return inter / (a1 + a2 - inter + EPS);
}

// Core per-cell loss (unchanged since R1, verified). Works on LDS or global.
__device__ __forceinline__ float cell_loss(const float* __restrict__ yt,
                                           const float* __restrict__ yp) {
    const float LAMBDA_COORD = 5.0f;
    const float LAMBDA_NOOBJ = 0.5f;
    const float EPS = 1e-6f;

    float obj = (yt[4] == 1.0f) ? 1.0f : 0.0f;
    float noobj = 1.0f - obj;

    float tb[4]  = {yt[0], yt[1], yt[2], yt[3]};
    float pb1[4] = {yp[0], yp[1], yp[2], yp[3]};
    float pb2[4] = {yp[5], yp[6], yp[7], yp[8]};
    float iou1 = iou_yolo(tb, pb1);
    float iou2 = iou_yolo(tb, pb2);
    bool best1 = iou1 > iou2;

    float bh0 = best1 ? yp[0] : yp[5];
    float bh1 = best1 ? yp[1] : yp[6];
    float bh2 = best1 ? yp[2] : yp[7];
    float bh3 = best1 ? yp[3] : yp[8];
    float conf_hat       = best1 ? yp[4] : yp[9];
    float other_conf_hat = best1 ? yp[9] : yp[4];

    float dx = yt[0] - bh0, dy = yt[1] - bh1;
    float xy = dx * dx + dy * dy;

    float sw = sqrtf(yt[2]) - sqrtf(fabsf(bh2 + EPS));
    float sh = sqrtf(yt[3]) - sqrtf(fabsf(bh3 + EPS));
    float wh = sw * sw + sh * sh;

    float dc = yt[4] - conf_hat;
    float obj_conf = dc * dc;

    float noobj_in_obj = LAMBDA_NOOBJ * other_conf_hat * other_conf_hat;

    float d4 = yt[4] - yp[4];
    float d9 = yt[4] - yp[9];
    float noobj_cells = LAMBDA_NOOBJ * (d4 * d4 + d9 * d9);

    float cls = 0.0f;
#pragma unroll
    for (int k = 10; k < DD; ++k) {
        float d = yt[k] - yp[k];
        cls += d * d;
    }

    return obj * (LAMBDA_COORD * (xy + wh) + obj_conf + noobj_in_obj + cls)
         + noobj * noobj_cells;
}

// Issue all 15 nt 16B loads of one tile into registers (no waits).
// idx<480 -> yt tile, else yp tile; per-lane select only at i==7.
__device__ __forceinline__ void load_tile_nt(f32x4 r[F4PL],
                                             const f32x4* __restrict__ gt4,
                                             const f32x4* __restrict__ gp4,
                                             int lane) {
#pragma unroll
    for (int i = 0; i < F4PL; ++i) {
        int idx = i * 64 + lane;
        const f32x4* src = (idx < HALF_F4) ? (gt4 + idx)
                                           : (gp4 + (idx - HALF_F4));
        r[i] = __builtin_nontemporal_load(src);
    }
    __builtin_amdgcn_sched_barrier(0);  // pin: loads issue before what follows
}

// Write the register tile to the wave's contiguous LDS buffer (linear in idx).
__device__ __forceinline__ void write_tile(const f32x4 r[F4PL],
                                           f32x4* __restrict__ l4, int lane) {
#pragma unroll
    for (int i = 0; i < F4PL; ++i)
        l4[i * 64 + lane] = r[i];
    __builtin_amdgcn_sched_barrier(0);
}

// Persistent free-running waves; wave-private LDS; software-pipelined:
// { ds_write(t); issue nt-loads(t+stride); compute(t) }.
// USE_WS=1: per-block partial -> partials[blockIdx.x]; USE_WS=0: atomic.
template <int USE_WS>
__global__ __launch_bounds__(BLOCK)
void yolo_loss_kernel(const float* __restrict__ yt_g,
                      const float* __restrict__ yp_g,
                      float* __restrict__ sink,
                      int ncells, float inv_batch) {
    // 4 waves x 3840 floats ([yt 1920 | yp 1920]) = 61440 B -> 2 blocks/CU.
    __shared__ __align__(16) float lbuf[WPB][2 * FPW];
    __shared__ float smem[WPB];

    const int tid  = threadIdx.x;
    const int lane = tid & 63;
    const int wave = tid >> 6;
    const int gwave  = blockIdx.x * WPB + wave;
    const int nwaves = gridDim.x * WPB;

    const int nwt_full   = ncells / CPW;           // full 64-cell tiles
    const int tail_cells = ncells - nwt_full * CPW;

    float* __restrict__ wb  = lbuf[wave];
    f32x4* __restrict__ wb4 = reinterpret_cast<f32x4*>(wb);

    float wsum = 0.0f;
    f32x4 r[F4PL];  // 60 VGPRs, statically indexed only (rule #20)

    int wt = gwave;
    if (wt < nwt_full) {
        const size_t fb = (size_t)wt * FPW;
        load_tile_nt(r, reinterpret_cast<const f32x4*>(yt_g + fb),
                        reinterpret_cast<const f32x4*>(yp_g + fb), lane);
    }
    while (wt < nwt_full) {
        const int next = wt + nwaves;

        // Drain current tile's loads into LDS (vmcnt waits amortized: these
        // loads were issued one compute-phase ago).
        write_tile(r, wb4, lane);

        // Prefetch next tile: loads in flight during compute below.
        if (next < nwt_full) {
            const size_t fb = (size_t)next * FPW;
            load_tile_nt(r, reinterpret_cast<const f32x4*>(yt_g + fb),
                            reinterpret_cast<const f32x4*>(yp_g + fb), lane);
        }

        // Full tile: all 64 lanes valid. lgkmcnt orders ds_write -> ds_read.
        wsum += cell_loss(&wb[lane * DD], &wb[FPW + lane * DD]);

        wt = next;
    }

    // Tail tile (ncells % 64 != 0; dormant on bench shapes): the owning wave
    // computes straight from global (<=63 cells, negligible).
    if (tail_cells != 0 && gwave == (nwt_full % nwaves)) {
        int c = nwt_full * CPW + lane;
        if (c < ncells)
            wsum += cell_loss(yt_g + (size_t)c * DD, yp_g + (size_t)c * DD);
    }

    // Final reduction: wave shuffle-reduce, one cross-wave barrier, one store.
#pragma unroll
    for (int off = 32; off > 0; off >>= 1)
        wsum += __shfl_down(wsum, off, 64);

    if (lane == 0) smem[wave] = wsum;
    __syncthreads();
    if (tid == 0) {
        float s = smem[0] + smem[1] + smem[2] + smem[3];
        if (USE_WS) sink[blockIdx.x] = s;
        else        atomicAdd(sink, s * inv_batch);
    }
}

// Second stage: one block sums the per-block partials and writes the scalar.
__global__ __launch_bounds__(256)
void reduce_kernel(const float* __restrict__ partials, float* __restrict__ out,
                   int n, float inv_batch) {
    float s = 0.0f;
    for (int i = threadIdx.x; i < n; i += 256) s += partials[i];
#pragma unroll
    for (int off = 32; off > 0; off >>= 1)
        s += __shfl_down(s, off, 64);
    __shared__ float sm[4];
    int lane = threadIdx.x & 63;
    int wave = threadIdx.x >> 6;
    if (lane == 0) sm[wave] = s;
    __syncthreads();
    if (threadIdx.x == 0)
        out[0] = (sm[0] + sm[1] + sm[2] + sm[3]) * inv_batch;
}

extern "C" void kernel_launch(void* const* d_in, const int* in_sizes, int n_in,
                              void* d_out, int out_size, void* d_ws, size_t ws_size,
                              hipStream_t stream) {
    const float* yt = (const float*)d_in[0];
    const float* yp = (const float*)d_in[1];
    float* out = (float*)d_out;
    float* ws = (float*)d_ws;

    int total = in_sizes[0];          // batch * S*S * D
    int ncells = total / DD;          // batch * 49
    int batch = ncells / SS;
    float inv_batch = 1.0f / (float)batch;

    int nwt = (ncells + CPW - 1) / CPW;
    int grid_needed = (nwt + WPB - 1) / WPB;
    int grid = grid_needed < PERSIST_GRID ? grid_needed : PERSIST_GRID;

    if (ws != nullptr && ws_size >= (size_t)grid * sizeof(float)) {
        yolo_loss_kernel<1><<<grid, BLOCK, 0, stream>>>(yt, yp, ws, ncells,
                                                        inv_batch);
        reduce_kernel<<<1, 256, 0, stream>>>(ws, out, grid, inv_batch);
    } else {
        // Fallback: atomic path (d_out is poisoned each launch -> memset).
        (void)hipMemsetAsync(out, 0, sizeof(float), stream);
        yolo_loss_kernel<0><<<grid, BLOCK, 0, stream>>>(yt, yp, out, ncells,
                                                        inv_batch);
    }
}